// Round 1
// baseline (1380.705 us; speedup 1.0000x reference)
//
#include <hip/hip_runtime.h>
#include <stdint.h>

typedef unsigned short ushort_t;
typedef unsigned int uint32;
typedef __attribute__((ext_vector_type(8))) short bfrag_t;   // 8 bf16 (4 VGPRs)
typedef __attribute__((ext_vector_type(4))) float facc_t;    // 4 fp32 acc

__device__ __forceinline__ uint32 f2bf(float f) {
    uint32 b = __float_as_uint(f);
    return (b + 0x7FFFu + ((b >> 16) & 1u)) >> 16;   // RNE
}

// ---------------- weight convert + transpose (W[K,Nsrc] fp32 -> WT[Npad,K] bf16) ----------------
__global__ void k_convT(const float* __restrict__ W, ushort_t* __restrict__ WT,
                        int K, int Nsrc, int Npad) {
    int i = blockIdx.x * 256 + threadIdx.x;
    int total = K * Npad;
    if (i >= total) return;
    int n = i / K, k = i - n * K;
    float v = (n < Nsrc) ? W[(size_t)k * Nsrc + n] : 0.f;
    WT[(size_t)n * K + k] = (ushort_t)f2bf(v);
}

// ---------------- degrees ----------------
__global__ void k_deg(const int* __restrict__ src, const int* __restrict__ dst,
                      int* degO, int* degI, int E) {
    int i = blockIdx.x * 256 + threadIdx.x;
    if (i < E) {
        atomicAdd(&degO[src[i]], 1);
        atomicAdd(&degI[dst[i]], 1);
    }
}

__global__ void k_inv(const int* __restrict__ degO, const int* __restrict__ degI,
                      float* invO, float* invI, int N) {
    int i = blockIdx.x * 256 + threadIdx.x;
    if (i < N) {
        invO[i] = 1.f / sqrtf(fmaxf((float)degO[i], 1.f));
        invI[i] = 1.f / sqrtf(fmaxf((float)degI[i], 1.f));
    }
}

// ---------------- exclusive scan (3-kernel hierarchical) ----------------
__global__ void k_scan1(const int* __restrict__ in, int* __restrict__ out,
                        int* __restrict__ bsum, int n) {
    __shared__ int s[1024];
    int tid = threadIdx.x;
    int i = blockIdx.x * 1024 + tid;
    int v = (i < n) ? in[i] : 0;
    s[tid] = v;
    __syncthreads();
    for (int o = 1; o < 1024; o <<= 1) {
        int t = (tid >= o) ? s[tid - o] : 0;
        __syncthreads();
        s[tid] += t;
        __syncthreads();
    }
    if (i < n) out[i] = s[tid] - v;          // exclusive
    if (tid == 1023) bsum[blockIdx.x] = s[1023];
}

__global__ void k_scan2(int* bsum, int nb) {
    if (threadIdx.x == 0 && blockIdx.x == 0) {
        int run = 0;
        for (int i = 0; i < nb; i++) { int v = bsum[i]; bsum[i] = run; run += v; }
    }
}

__global__ void k_scan3(int* __restrict__ out, const int* __restrict__ bsum, int n) {
    int i = blockIdx.x * 1024 + threadIdx.x;
    if (i < n) out[i] += bsum[blockIdx.x];
}

// ---------------- edge placement into dst-CSR ----------------
__global__ void k_place(const int* __restrict__ src, const int* __restrict__ dst,
                        const int* __restrict__ offs, int* cnt,
                        int* __restrict__ sorted, int E) {
    int i = blockIdx.x * 256 + threadIdx.x;
    if (i < E) {
        int d = dst[i];
        int pos = offs[d] + atomicAdd(&cnt[d], 1);
        sorted[pos] = src[i];
    }
}

// ---------------- MFMA GEMM: [M,K] x [K,128] -> [M, ldout] (stores cols < nstore) ----------------
// A supplied as fp32 (converted on the fly) or bf16; supports K-split concat (A0|A1).
// BT is bf16 [128][K] (n-major). bias fp32[nstore] or null. RELU optional.
template<bool A_BF16, bool RELU, bool OUT_BF16>
__global__ __launch_bounds__(256)
void k_gemm(const void* __restrict__ A0, const void* __restrict__ A1, int Ksplit,
            const ushort_t* __restrict__ BT, int K,
            const float* __restrict__ bias,
            void* __restrict__ out, int ldout, int nstore, int M)
{
    constexpr int ST = 56;                 // LDS row stride (elements): 112B = 7x16B, 2-way-max banks
    __shared__ ushort_t As[128 * ST];
    __shared__ ushort_t Bs[128 * ST];

    const int tid = threadIdx.x;
    const int lane = tid & 63;
    const int wid = tid >> 6;
    const int row_off = (wid & 1) * 64;
    const int col_off = (wid >> 1) * 64;
    const int lrow = lane & 15;
    const int lk = (lane >> 4) * 8;
    const int block_row = blockIdx.x * 128;

    facc_t acc[4][4];
#pragma unroll
    for (int mi = 0; mi < 4; mi++)
#pragma unroll
        for (int ni = 0; ni < 4; ni++)
            acc[mi][ni] = (facc_t){0.f, 0.f, 0.f, 0.f};

    const int r = tid >> 1;                // 0..127 : tile row / B n-row
    const int halfk = (tid & 1) * 16;      // 0 or 16
    int grow = block_row + r;
    if (grow > M - 1) grow = M - 1;        // clamp loads; stores masked

    const int nk = K / 32;
    for (int kt = 0; kt < nk; ++kt) {
        const int kglob = kt * 32 + halfk;
        __syncthreads();
        // ---- stage A (128 x 32 bf16) ----
        {
            const void* srcp; int kk, lda_;
            if (kglob < Ksplit) { srcp = A0; kk = kglob; lda_ = Ksplit; }
            else { srcp = A1; kk = kglob - Ksplit; lda_ = K - Ksplit; }
            if constexpr (A_BF16) {
                const uint4* ap = (const uint4*)((const ushort_t*)srcp + (size_t)grow * lda_ + kk);
                uint4 u0 = ap[0], u1 = ap[1];
                *(uint4*)&As[r * ST + halfk] = u0;
                *(uint4*)&As[r * ST + halfk + 8] = u1;
            } else {
                const float* ap = (const float*)srcp + (size_t)grow * lda_ + kk;
                float4 f0 = ((const float4*)ap)[0];
                float4 f1 = ((const float4*)ap)[1];
                float4 f2 = ((const float4*)ap)[2];
                float4 f3 = ((const float4*)ap)[3];
                uint4 o0, o1;
                o0.x = f2bf(f0.x) | (f2bf(f0.y) << 16);
                o0.y = f2bf(f0.z) | (f2bf(f0.w) << 16);
                o0.z = f2bf(f1.x) | (f2bf(f1.y) << 16);
                o0.w = f2bf(f1.z) | (f2bf(f1.w) << 16);
                o1.x = f2bf(f2.x) | (f2bf(f2.y) << 16);
                o1.y = f2bf(f2.z) | (f2bf(f2.w) << 16);
                o1.z = f2bf(f3.x) | (f2bf(f3.y) << 16);
                o1.w = f2bf(f3.z) | (f2bf(f3.w) << 16);
                *(uint4*)&As[r * ST + halfk] = o0;
                *(uint4*)&As[r * ST + halfk + 8] = o1;
            }
        }
        // ---- stage B (128 n x 32 k bf16) from pre-transposed BT ----
        {
            const uint4* bp = (const uint4*)(BT + (size_t)r * K + kglob);
            uint4 b0 = bp[0], b1 = bp[1];
            *(uint4*)&Bs[r * ST + halfk] = b0;
            *(uint4*)&Bs[r * ST + halfk + 8] = b1;
        }
        __syncthreads();
        // ---- MFMA: 4x4 tiles of 16x16x32 per wave (wave tile 64x64) ----
        bfrag_t af[4], bf[4];
#pragma unroll
        for (int mi = 0; mi < 4; mi++)
            af[mi] = *(const bfrag_t*)&As[(row_off + mi * 16 + lrow) * ST + lk];
#pragma unroll
        for (int ni = 0; ni < 4; ni++)
            bf[ni] = *(const bfrag_t*)&Bs[(col_off + ni * 16 + lrow) * ST + lk];
#pragma unroll
        for (int mi = 0; mi < 4; mi++)
#pragma unroll
            for (int ni = 0; ni < 4; ni++)
                acc[mi][ni] = __builtin_amdgcn_mfma_f32_16x16x32_bf16(af[mi], bf[ni], acc[mi][ni], 0, 0, 0);
    }

    // ---- epilogue: C/D layout col=lane&15, row=(lane>>4)*4+reg (m89-verified) ----
    const int qrow = (lane >> 4) * 4;
#pragma unroll
    for (int mi = 0; mi < 4; mi++) {
#pragma unroll
        for (int ni = 0; ni < 4; ni++) {
            int col = col_off + ni * 16 + lrow;
            if (col >= nstore) continue;
            float badd = bias ? bias[col] : 0.f;
#pragma unroll
            for (int rr = 0; rr < 4; rr++) {
                int gr = block_row + row_off + mi * 16 + qrow + rr;
                if (gr >= M) continue;
                float v = acc[mi][ni][rr] + badd;
                if (RELU) v = fmaxf(v, 0.f);
                if (OUT_BF16)
                    ((ushort_t*)out)[(size_t)gr * ldout + col] = (ushort_t)f2bf(v);
                else
                    ((float*)out)[(size_t)gr * ldout + col] = v;
            }
        }
    }
}

// ---------------- gather-side aggregation: h[i] = sum_in-edges norm * t[src] + bias ----------------
// wave per node, lane handles 2 cols (128 cols); t is bf16 [N,128]
__global__ __launch_bounds__(256)
void k_agg(const ushort_t* __restrict__ t, const int* __restrict__ offs,
           const int* __restrict__ degI, const int* __restrict__ sorted,
           const float* __restrict__ invO, const float* __restrict__ invI,
           const float* __restrict__ bias, float* __restrict__ h, int N)
{
    int lane = threadIdx.x & 63;
    int node = blockIdx.x * 4 + (threadIdx.x >> 6);
    if (node >= N) return;
    int start = offs[node];
    int deg = degI[node];
    float invi = invI[node];
    float a0 = 0.f, a1 = 0.f;
    const uint32* tp = (const uint32*)t;
    for (int j = 0; j < deg; j++) {
        int s = sorted[start + j];
        float nrm = invO[s] * invi;
        uint32 u = tp[(size_t)s * 64 + lane];
        a0 += __uint_as_float(u << 16) * nrm;           // col 2*lane
        a1 += __uint_as_float(u & 0xFFFF0000u) * nrm;   // col 2*lane+1
    }
    h[(size_t)node * 128 + 2 * lane]     = a0 + bias[2 * lane];
    h[(size_t)node * 128 + 2 * lane + 1] = a1 + bias[2 * lane + 1];
}

// ---------------- logits_final = (C + Ut + Uv) / 3 ----------------
__global__ void k_combine(float* __restrict__ out, int n40) {
    int i = blockIdx.x * 256 + threadIdx.x;
    if (i < n40)
        out[i] = (out[n40 + i] + out[2 * n40 + i] + out[3 * n40 + i]) * (1.f / 3.f);
}

extern "C" void kernel_launch(void* const* d_in, const int* in_sizes, int n_in,
                              void* d_out, int out_size, void* d_ws, size_t ws_size,
                              hipStream_t stream) {
    const float* text = (const float*)d_in[0];
    const float* vis  = (const float*)d_in[1];
    const int* esrc   = (const int*)d_in[2];
    const int* edst   = (const int*)d_in[3];
    const float* W_t   = (const float*)d_in[4];
    const float* b_t   = (const float*)d_in[5];
    const float* W_v   = (const float*)d_in[6];
    const float* b_v   = (const float*)d_in[7];
    const float* W_mp0 = (const float*)d_in[8];
    const float* b_mp0 = (const float*)d_in[9];
    const float* W_mp1 = (const float*)d_in[10];
    const float* b_mp1 = (const float*)d_in[11];
    const float* W_c   = (const float*)d_in[12];
    const float* b_c   = (const float*)d_in[13];
    const float* W_ut  = (const float*)d_in[14];
    const float* b_ut  = (const float*)d_in[15];
    const float* W_uv  = (const float*)d_in[16];
    const float* b_uv  = (const float*)d_in[17];

    const int N = in_sizes[0] / 768;   // 100000
    const int E = in_sizes[2];         // 1600000

    // ---- workspace layout (~137 MB) ----
    char* w = (char*)d_ws;
    auto alloc = [&](size_t b) { char* p = w; w += (b + 255) & ~(size_t)255; return p; };
    ushort_t* et   = (ushort_t*)alloc((size_t)N * 128 * 2);
    ushort_t* ev   = (ushort_t*)alloc((size_t)N * 128 * 2);
    ushort_t* tbuf = (ushort_t*)alloc((size_t)N * 128 * 2);
    float*    h    = (float*)alloc((size_t)N * 128 * 4);
    ushort_t* WtT   = (ushort_t*)alloc((size_t)128 * 768 * 2);
    ushort_t* WvT   = (ushort_t*)alloc((size_t)128 * 512 * 2);
    ushort_t* Wmp0T = (ushort_t*)alloc((size_t)128 * 256 * 2);
    ushort_t* Wmp1T = (ushort_t*)alloc((size_t)128 * 128 * 2);
    ushort_t* WcT   = (ushort_t*)alloc((size_t)128 * 128 * 2);
    ushort_t* WutT  = (ushort_t*)alloc((size_t)128 * 128 * 2);
    ushort_t* WuvT  = (ushort_t*)alloc((size_t)128 * 128 * 2);
    int*   degO   = (int*)alloc((size_t)N * 4);
    int*   degI   = (int*)alloc((size_t)N * 4);
    int*   cnt    = (int*)alloc((size_t)N * 4);
    float* invO   = (float*)alloc((size_t)N * 4);
    float* invI   = (float*)alloc((size_t)N * 4);
    int*   offs   = (int*)alloc((size_t)N * 4);
    int*   bsum   = (int*)alloc(1024 * 4);
    int*   sorted = (int*)alloc((size_t)E * 4);

    hipMemsetAsync(degO, 0, (size_t)N * 4, stream);
    hipMemsetAsync(degI, 0, (size_t)N * 4, stream);
    hipMemsetAsync(cnt,  0, (size_t)N * 4, stream);

    // weight prep (bf16, transposed, heads zero-padded to N=128)
    auto conv = [&](const float* W, ushort_t* WT, int K, int Nsrc, int Npad) {
        int tot = K * Npad;
        k_convT<<<(tot + 255) / 256, 256, 0, stream>>>(W, WT, K, Nsrc, Npad);
    };
    conv(W_t,   WtT,   768, 128, 128);
    conv(W_v,   WvT,   512, 128, 128);
    conv(W_mp0, Wmp0T, 256, 128, 128);
    conv(W_mp1, Wmp1T, 128, 128, 128);
    conv(W_c,   WcT,   128, 40, 128);
    conv(W_ut,  WutT,  128, 40, 128);
    conv(W_uv,  WuvT,  128, 40, 128);

    // graph structure
    k_deg<<<(E + 255) / 256, 256, 0, stream>>>(esrc, edst, degO, degI, E);
    k_inv<<<(N + 255) / 256, 256, 0, stream>>>(degO, degI, invO, invI, N);
    int nb = (N + 1023) / 1024;
    k_scan1<<<nb, 1024, 0, stream>>>(degI, offs, bsum, N);
    k_scan2<<<1, 1, 0, stream>>>(bsum, nb);
    k_scan3<<<nb, 1024, 0, stream>>>(offs, bsum, N);
    k_place<<<(E + 255) / 256, 256, 0, stream>>>(esrc, edst, offs, cnt, sorted, E);

    const int gm = (N + 127) / 128;
    // modality encoders (fp32 in, relu, bf16 out)
    k_gemm<false, true, true><<<gm, 256, 0, stream>>>(text, nullptr, 768, WtT, 768, b_t, et, 128, 128, N);
    k_gemm<false, true, true><<<gm, 256, 0, stream>>>(vis,  nullptr, 512, WvT, 512, b_v, ev, 128, 128, N);
    // GCN layer 0: t = concat(et,ev) @ W_mp0 ; h = agg(t) + b_mp0
    k_gemm<true, false, true><<<gm, 256, 0, stream>>>(et, ev, 128, Wmp0T, 256, nullptr, tbuf, 128, 128, N);
    k_agg<<<(N + 3) / 4, 256, 0, stream>>>(tbuf, offs, degI, sorted, invO, invI, b_mp0, h, N);
    // GCN layer 1
    k_gemm<false, false, true><<<gm, 256, 0, stream>>>(h, nullptr, 128, Wmp1T, 128, nullptr, tbuf, 128, 128, N);
    k_agg<<<(N + 3) / 4, 256, 0, stream>>>(tbuf, offs, degI, sorted, invO, invI, b_mp1, h, N);

    // heads (fp32 out into d_out segments), then combine
    float* out = (float*)d_out;
    const size_t n40 = (size_t)N * 40;
    k_gemm<false, false, false><<<gm, 256, 0, stream>>>(h,  nullptr, 128, WcT,  128, b_c,  out + n40,     40, 40, N);
    k_gemm<true,  false, false><<<gm, 256, 0, stream>>>(et, nullptr, 128, WutT, 128, b_ut, out + 2 * n40, 40, 40, N);
    k_gemm<true,  false, false><<<gm, 256, 0, stream>>>(ev, nullptr, 128, WuvT, 128, b_uv, out + 3 * n40, 40, 40, N);
    k_combine<<<(int)((n40 + 255) / 256), 256, 0, stream>>>(out, (int)n40);
}

// Round 2
// 1136.264 us; speedup vs baseline: 1.2151x; 1.2151x over previous
//
#include <hip/hip_runtime.h>
#include <stdint.h>

typedef unsigned short ushort_t;
typedef unsigned int uint32;
typedef __attribute__((ext_vector_type(8))) short bfrag_t;   // 8 bf16 (4 VGPRs)
typedef __attribute__((ext_vector_type(4))) float facc_t;    // 4 fp32 acc

__device__ __forceinline__ uint32 f2bf(float f) {
    uint32 b = __float_as_uint(f);
    return (b + 0x7FFFu + ((b >> 16) & 1u)) >> 16;   // RNE
}

// ---------------- all weight converts in one dispatch ----------------
// W[K,Nsrc] fp32 -> WT[Npad=128,K] bf16, 7 regions
struct ConvArgs {
    const float* W[7];
    ushort_t* WT[7];
    int K[7];
    int Nsrc[7];
    int start[8];   // cumulative element offsets (K*128 per region)
};

__global__ void k_convAll(ConvArgs a) {
    int i = blockIdx.x * 256 + threadIdx.x;
#pragma unroll
    for (int g = 0; g < 7; g++) {
        if (i >= a.start[g] && i < a.start[g + 1]) {
            int li = i - a.start[g];
            int K = a.K[g];
            int n = li / K, k = li - n * K;
            float v = (n < a.Nsrc[g]) ? a.W[g][(size_t)k * a.Nsrc[g] + n] : 0.f;
            a.WT[g][(size_t)n * K + k] = (ushort_t)f2bf(v);
        }
    }
}

// ---------------- degrees ----------------
__global__ void k_deg(const int* __restrict__ src, const int* __restrict__ dst,
                      int* degO, int* degI, int E) {
    int i = blockIdx.x * 256 + threadIdx.x;
    if (i < E) {
        atomicAdd(&degO[src[i]], 1);
        atomicAdd(&degI[dst[i]], 1);
    }
}

// ---------------- exclusive scan (3-kernel hierarchical) ----------------
__global__ void k_scan1(const int* __restrict__ in, int* __restrict__ out,
                        int* __restrict__ bsum, int n) {
    __shared__ int s[1024];
    int tid = threadIdx.x;
    int i = blockIdx.x * 1024 + tid;
    int v = (i < n) ? in[i] : 0;
    s[tid] = v;
    __syncthreads();
    for (int o = 1; o < 1024; o <<= 1) {
        int t = (tid >= o) ? s[tid - o] : 0;
        __syncthreads();
        s[tid] += t;
        __syncthreads();
    }
    if (i < n) out[i] = s[tid] - v;          // exclusive
    if (tid == 1023) bsum[blockIdx.x] = s[1023];
}

// parallel block-sum scan (nb <= 1024)
__global__ void k_scan2(int* bsum, int nb) {
    __shared__ int s[1024];
    int tid = threadIdx.x;
    int v = (tid < nb) ? bsum[tid] : 0;
    s[tid] = v;
    __syncthreads();
    for (int o = 1; o < 1024; o <<= 1) {
        int t = (tid >= o) ? s[tid - o] : 0;
        __syncthreads();
        s[tid] += t;
        __syncthreads();
    }
    if (tid < nb) bsum[tid] = s[tid] - v;    // exclusive
}

// scan finalize + inverse-sqrt degrees (fused)
__global__ void k_scan3(int* __restrict__ out, const int* __restrict__ bsum,
                        const int* __restrict__ degO, const int* __restrict__ degI,
                        float* __restrict__ invO, float* __restrict__ invI, int n) {
    int i = blockIdx.x * 1024 + threadIdx.x;
    if (i < n) {
        out[i] += bsum[blockIdx.x];
        invO[i] = rsqrtf(fmaxf((float)degO[i], 1.f));
        invI[i] = rsqrtf(fmaxf((float)degI[i], 1.f));
    }
}

// ---------------- edge placement into dst-CSR, packing (src, invO[src]) ----------------
__global__ void k_place(const int* __restrict__ src, const int* __restrict__ dst,
                        const int* __restrict__ offs, int* cnt,
                        const float* __restrict__ invO,
                        int2* __restrict__ ep, int E) {
    int i = blockIdx.x * 256 + threadIdx.x;
    if (i < E) {
        int d = dst[i];
        int s = src[i];
        int pos = offs[d] + atomicAdd(&cnt[d], 1);
        ep[pos] = make_int2(s, __float_as_int(invO[s]));
    }
}

// ---------------- MFMA GEMM: [M,K] x [K,128] -> [M, ldout] (stores cols < nstore) ----------------
template<bool A_BF16, bool RELU, bool OUT_BF16>
__global__ __launch_bounds__(256)
void k_gemm(const void* __restrict__ A0, const void* __restrict__ A1, int Ksplit,
            const ushort_t* __restrict__ BT, int K,
            const float* __restrict__ bias,
            void* __restrict__ out, int ldout, int nstore, int M)
{
    constexpr int ST = 56;                 // LDS row stride (elements): 112B, 2-way-max banks
    __shared__ ushort_t As[128 * ST];
    __shared__ ushort_t Bs[128 * ST];

    const int tid = threadIdx.x;
    const int lane = tid & 63;
    const int wid = tid >> 6;
    const int row_off = (wid & 1) * 64;
    const int col_off = (wid >> 1) * 64;
    const int lrow = lane & 15;
    const int lk = (lane >> 4) * 8;
    const int block_row = blockIdx.x * 128;

    facc_t acc[4][4];
#pragma unroll
    for (int mi = 0; mi < 4; mi++)
#pragma unroll
        for (int ni = 0; ni < 4; ni++)
            acc[mi][ni] = (facc_t){0.f, 0.f, 0.f, 0.f};

    const int r = tid >> 1;                // 0..127 : tile row / B n-row
    const int halfk = (tid & 1) * 16;      // 0 or 16
    int grow = block_row + r;
    if (grow > M - 1) grow = M - 1;        // clamp loads; stores masked

    const int nk = K / 32;
    for (int kt = 0; kt < nk; ++kt) {
        const int kglob = kt * 32 + halfk;
        __syncthreads();
        // ---- stage A (128 x 32 bf16) ----
        {
            const void* srcp; int kk, lda_;
            if (kglob < Ksplit) { srcp = A0; kk = kglob; lda_ = Ksplit; }
            else { srcp = A1; kk = kglob - Ksplit; lda_ = K - Ksplit; }
            if constexpr (A_BF16) {
                const uint4* ap = (const uint4*)((const ushort_t*)srcp + (size_t)grow * lda_ + kk);
                uint4 u0 = ap[0], u1 = ap[1];
                *(uint4*)&As[r * ST + halfk] = u0;
                *(uint4*)&As[r * ST + halfk + 8] = u1;
            } else {
                const float* ap = (const float*)srcp + (size_t)grow * lda_ + kk;
                float4 f0 = ((const float4*)ap)[0];
                float4 f1 = ((const float4*)ap)[1];
                float4 f2 = ((const float4*)ap)[2];
                float4 f3 = ((const float4*)ap)[3];
                uint4 o0, o1;
                o0.x = f2bf(f0.x) | (f2bf(f0.y) << 16);
                o0.y = f2bf(f0.z) | (f2bf(f0.w) << 16);
                o0.z = f2bf(f1.x) | (f2bf(f1.y) << 16);
                o0.w = f2bf(f1.z) | (f2bf(f1.w) << 16);
                o1.x = f2bf(f2.x) | (f2bf(f2.y) << 16);
                o1.y = f2bf(f2.z) | (f2bf(f2.w) << 16);
                o1.z = f2bf(f3.x) | (f2bf(f3.y) << 16);
                o1.w = f2bf(f3.z) | (f2bf(f3.w) << 16);
                *(uint4*)&As[r * ST + halfk] = o0;
                *(uint4*)&As[r * ST + halfk + 8] = o1;
            }
        }
        // ---- stage B (128 n x 32 k bf16) from pre-transposed BT ----
        {
            const uint4* bp = (const uint4*)(BT + (size_t)r * K + kglob);
            uint4 b0 = bp[0], b1 = bp[1];
            *(uint4*)&Bs[r * ST + halfk] = b0;
            *(uint4*)&Bs[r * ST + halfk + 8] = b1;
        }
        __syncthreads();
        // ---- MFMA: 4x4 tiles of 16x16x32 per wave (wave tile 64x64) ----
        bfrag_t af[4], bf[4];
#pragma unroll
        for (int mi = 0; mi < 4; mi++)
            af[mi] = *(const bfrag_t*)&As[(row_off + mi * 16 + lrow) * ST + lk];
#pragma unroll
        for (int ni = 0; ni < 4; ni++)
            bf[ni] = *(const bfrag_t*)&Bs[(col_off + ni * 16 + lrow) * ST + lk];
#pragma unroll
        for (int mi = 0; mi < 4; mi++)
#pragma unroll
            for (int ni = 0; ni < 4; ni++)
                acc[mi][ni] = __builtin_amdgcn_mfma_f32_16x16x32_bf16(af[mi], bf[ni], acc[mi][ni], 0, 0, 0);
    }

    // ---- epilogue: C/D layout col=lane&15, row=(lane>>4)*4+reg (m89-verified) ----
    const int qrow = (lane >> 4) * 4;
#pragma unroll
    for (int mi = 0; mi < 4; mi++) {
#pragma unroll
        for (int ni = 0; ni < 4; ni++) {
            int col = col_off + ni * 16 + lrow;
            if (col >= nstore) continue;
            float badd = bias ? bias[col] : 0.f;
#pragma unroll
            for (int rr = 0; rr < 4; rr++) {
                int gr = block_row + row_off + mi * 16 + qrow + rr;
                if (gr >= M) continue;
                float v = acc[mi][ni][rr] + badd;
                if (RELU) v = fmaxf(v, 0.f);
                if (OUT_BF16)
                    ((ushort_t*)out)[(size_t)gr * ldout + col] = (ushort_t)f2bf(v);
                else
                    ((float*)out)[(size_t)gr * ldout + col] = v;
            }
        }
    }
}

// ---------------- gather-side aggregation: h[i] = invI[i]*sum(invO[s]*t[s]) + bias ----------------
// wave per node, lane handles 2 cols (128 cols); t is bf16 [N,128]; edges pre-packed (src, invO[src])
__global__ __launch_bounds__(256)
void k_agg(const ushort_t* __restrict__ t, const int* __restrict__ offs,
           const int* __restrict__ degI, const int2* __restrict__ ep,
           const float* __restrict__ invI,
           const float* __restrict__ bias, float* __restrict__ h, int N)
{
    int lane = threadIdx.x & 63;
    int node = blockIdx.x * 4 + (threadIdx.x >> 6);
    if (node >= N) return;
    int start = offs[node];
    int deg = degI[node];
    const uint32* tp = (const uint32*)t;
    float a0 = 0.f, a1 = 0.f;
    int j = 0;
    for (; j + 4 <= deg; j += 4) {
        int2 e0 = ep[start + j];
        int2 e1 = ep[start + j + 1];
        int2 e2 = ep[start + j + 2];
        int2 e3 = ep[start + j + 3];
        uint32 u0 = tp[(size_t)e0.x * 64 + lane];
        uint32 u1 = tp[(size_t)e1.x * 64 + lane];
        uint32 u2 = tp[(size_t)e2.x * 64 + lane];
        uint32 u3 = tp[(size_t)e3.x * 64 + lane];
        float n0 = __int_as_float(e0.y), n1 = __int_as_float(e1.y);
        float n2 = __int_as_float(e2.y), n3 = __int_as_float(e3.y);
        a0 += __uint_as_float(u0 << 16) * n0;
        a1 += __uint_as_float(u0 & 0xFFFF0000u) * n0;
        a0 += __uint_as_float(u1 << 16) * n1;
        a1 += __uint_as_float(u1 & 0xFFFF0000u) * n1;
        a0 += __uint_as_float(u2 << 16) * n2;
        a1 += __uint_as_float(u2 & 0xFFFF0000u) * n2;
        a0 += __uint_as_float(u3 << 16) * n3;
        a1 += __uint_as_float(u3 & 0xFFFF0000u) * n3;
    }
    for (; j < deg; j++) {
        int2 e = ep[start + j];
        uint32 u = tp[(size_t)e.x * 64 + lane];
        float nrm = __int_as_float(e.y);
        a0 += __uint_as_float(u << 16) * nrm;
        a1 += __uint_as_float(u & 0xFFFF0000u) * nrm;
    }
    float invi = invI[node];
    h[(size_t)node * 128 + 2 * lane]     = a0 * invi + bias[2 * lane];
    h[(size_t)node * 128 + 2 * lane + 1] = a1 * invi + bias[2 * lane + 1];
}

// ---------------- fused heads: C = h@Wc+bc, Ut = et@Wut+but, Uv = ev@Wuv+buv,
// final = (C+Ut+Uv)/3. Writes all 4 outputs [M,40] fp32.
// Block: 256 thr (4 waves), M-tile 128 (wave owns 32 rows), N-tile 64 (only 40 stored).
__global__ __launch_bounds__(256)
void k_heads(const float* __restrict__ h, const ushort_t* __restrict__ et,
             const ushort_t* __restrict__ ev,
             const ushort_t* __restrict__ WcT, const ushort_t* __restrict__ WutT,
             const ushort_t* __restrict__ WuvT,
             const float* __restrict__ b_c, const float* __restrict__ b_ut,
             const float* __restrict__ b_uv,
             float* __restrict__ out, int NC, int M)
{
    constexpr int ST = 136;              // 128 k + 8 pad (272B rows: 2-way max banks)
    __shared__ ushort_t As[128 * ST];    // 34.8 KB
    __shared__ ushort_t Bs[64 * ST];     // 17.4 KB

    const int tid = threadIdx.x;
    const int lane = tid & 63;
    const int wid = tid >> 6;
    const int row_off = wid * 32;
    const int lrow = lane & 15;
    const int lkbase = (lane >> 4) * 8;
    const int qrow = (lane >> 4) * 4;
    const int block_row = blockIdx.x * 128;

    const int r = tid >> 1;              // staging row 0..127
    const int half = (tid & 1) * 64;     // staging k-offset
    int grow = block_row + r;
    if (grow > M - 1) grow = M - 1;

    const int rb = tid >> 2;             // B staging row 0..63
    const int ob = (tid & 3) * 32;       // B staging k-offset

    facc_t sum[2][4];
#pragma unroll
    for (int mi = 0; mi < 2; mi++)
#pragma unroll
        for (int ni = 0; ni < 4; ni++)
            sum[mi][ni] = (facc_t){0.f, 0.f, 0.f, 0.f};

    for (int src = 0; src < 3; ++src) {
        __syncthreads();                 // previous LDS reads done
        // ---- stage B (64 n-rows x 128 k) ----
        {
            const ushort_t* WT = (src == 0) ? WcT : (src == 1) ? WutT : WuvT;
            const uint4* wp = (const uint4*)(WT + rb * 128 + ob);
            uint4* bp = (uint4*)&Bs[rb * ST + ob];
            bp[0] = wp[0]; bp[1] = wp[1]; bp[2] = wp[2]; bp[3] = wp[3];
        }
        // ---- stage A (128 rows x 128 k) ----
        if (src == 0) {
            const float* ap = h + (size_t)grow * 128 + half;
            uint4* dst = (uint4*)&As[r * ST + half];
#pragma unroll
            for (int q = 0; q < 8; q++) {
                float4 f0 = ((const float4*)ap)[2 * q];
                float4 f1 = ((const float4*)ap)[2 * q + 1];
                uint4 o;
                o.x = f2bf(f0.x) | (f2bf(f0.y) << 16);
                o.y = f2bf(f0.z) | (f2bf(f0.w) << 16);
                o.z = f2bf(f1.x) | (f2bf(f1.y) << 16);
                o.w = f2bf(f1.z) | (f2bf(f1.w) << 16);
                dst[q] = o;
            }
        } else {
            const ushort_t* ap = ((src == 1) ? et : ev) + (size_t)grow * 128 + half;
            const uint4* sp = (const uint4*)ap;
            uint4* dst = (uint4*)&As[r * ST + half];
#pragma unroll
            for (int q = 0; q < 8; q++) dst[q] = sp[q];
        }
        __syncthreads();
        // ---- compute 32x64 wave tile over K=128 ----
        facc_t acc[2][4];
#pragma unroll
        for (int mi = 0; mi < 2; mi++)
#pragma unroll
            for (int ni = 0; ni < 4; ni++)
                acc[mi][ni] = (facc_t){0.f, 0.f, 0.f, 0.f};
#pragma unroll
        for (int kt = 0; kt < 4; kt++) {
            int lk = kt * 32 + lkbase;
            bfrag_t af[2], bf[4];
#pragma unroll
            for (int mi = 0; mi < 2; mi++)
                af[mi] = *(const bfrag_t*)&As[(row_off + mi * 16 + lrow) * ST + lk];
#pragma unroll
            for (int ni = 0; ni < 4; ni++)
                bf[ni] = *(const bfrag_t*)&Bs[(ni * 16 + lrow) * ST + lk];
#pragma unroll
            for (int mi = 0; mi < 2; mi++)
#pragma unroll
                for (int ni = 0; ni < 4; ni++)
                    acc[mi][ni] = __builtin_amdgcn_mfma_f32_16x16x32_bf16(af[mi], bf[ni], acc[mi][ni], 0, 0, 0);
        }
        // ---- per-source epilogue + accumulate sum ----
        const float* bias = (src == 0) ? b_c : (src == 1) ? b_ut : b_uv;
        float* outS = out + (size_t)(src + 1) * M * NC;
#pragma unroll
        for (int mi = 0; mi < 2; mi++) {
#pragma unroll
            for (int ni = 0; ni < 4; ni++) {
                sum[mi][ni] += acc[mi][ni];
                int col = ni * 16 + lrow;
                if (col >= NC) continue;
                float badd = bias[col];
#pragma unroll
                for (int rr = 0; rr < 4; rr++) {
                    int gr = block_row + row_off + mi * 16 + qrow + rr;
                    if (gr >= M) continue;
                    outS[(size_t)gr * NC + col] = acc[mi][ni][rr] + badd;
                }
            }
        }
    }
    // ---- final = (sum + b_c+b_ut+b_uv) / 3 ----
#pragma unroll
    for (int mi = 0; mi < 2; mi++) {
#pragma unroll
        for (int ni = 0; ni < 4; ni++) {
            int col = ni * 16 + lrow;
            if (col >= NC) continue;
            float bs3 = b_c[col] + b_ut[col] + b_uv[col];
#pragma unroll
            for (int rr = 0; rr < 4; rr++) {
                int gr = block_row + row_off + mi * 16 + qrow + rr;
                if (gr >= M) continue;
                out[(size_t)gr * NC + col] = (sum[mi][ni][rr] + bs3) * (1.f / 3.f);
            }
        }
    }
}

extern "C" void kernel_launch(void* const* d_in, const int* in_sizes, int n_in,
                              void* d_out, int out_size, void* d_ws, size_t ws_size,
                              hipStream_t stream) {
    const float* text = (const float*)d_in[0];
    const float* vis  = (const float*)d_in[1];
    const int* esrc   = (const int*)d_in[2];
    const int* edst   = (const int*)d_in[3];
    const float* W_t   = (const float*)d_in[4];
    const float* b_t   = (const float*)d_in[5];
    const float* W_v   = (const float*)d_in[6];
    const float* b_v   = (const float*)d_in[7];
    const float* W_mp0 = (const float*)d_in[8];
    const float* b_mp0 = (const float*)d_in[9];
    const float* W_mp1 = (const float*)d_in[10];
    const float* b_mp1 = (const float*)d_in[11];
    const float* W_c   = (const float*)d_in[12];
    const float* b_c   = (const float*)d_in[13];
    const float* W_ut  = (const float*)d_in[14];
    const float* b_ut  = (const float*)d_in[15];
    const float* W_uv  = (const float*)d_in[16];
    const float* b_uv  = (const float*)d_in[17];

    const int D_TEXT = 768, D_VIS = 512, D_EMB = 128;
    const int NC = in_sizes[13];            // 40
    const int N = in_sizes[0] / D_TEXT;     // 100000
    const int E = in_sizes[2];              // 1600000

    // ---- workspace layout ----
    char* w = (char*)d_ws;
    auto alloc = [&](size_t b) { char* p = w; w += (b + 255) & ~(size_t)255; return p; };
    ushort_t* et   = (ushort_t*)alloc((size_t)N * 128 * 2);
    ushort_t* ev   = (ushort_t*)alloc((size_t)N * 128 * 2);
    ushort_t* tbuf = (ushort_t*)alloc((size_t)N * 128 * 2);
    float*    h    = (float*)alloc((size_t)N * 128 * 4);
    ushort_t* WtT   = (ushort_t*)alloc((size_t)128 * 768 * 2);
    ushort_t* WvT   = (ushort_t*)alloc((size_t)128 * 512 * 2);
    ushort_t* Wmp0T = (ushort_t*)alloc((size_t)128 * 256 * 2);
    ushort_t* Wmp1T = (ushort_t*)alloc((size_t)128 * 128 * 2);
    ushort_t* WcT   = (ushort_t*)alloc((size_t)128 * 128 * 2);
    ushort_t* WutT  = (ushort_t*)alloc((size_t)128 * 128 * 2);
    ushort_t* WuvT  = (ushort_t*)alloc((size_t)128 * 128 * 2);
    int*   degO   = (int*)alloc((size_t)N * 4);
    int*   degI   = (int*)alloc((size_t)N * 4);
    int*   cnt    = (int*)alloc((size_t)N * 4);
    float* invO   = (float*)alloc((size_t)N * 4);
    float* invI   = (float*)alloc((size_t)N * 4);
    int*   offs   = (int*)alloc((size_t)N * 4);
    int*   bsum   = (int*)alloc(1024 * 4);
    int2*  ep     = (int2*)alloc((size_t)E * 8);

    // one memset covers degO|degI|cnt (allocated contiguously)
    hipMemsetAsync(degO, 0, (size_t)((char*)cnt - (char*)degO) + (size_t)N * 4, stream);

    // ---- weight prep: 7 converts, 1 dispatch ----
    {
        ConvArgs a;
        const float* Ws[7]  = {W_t, W_v, W_mp0, W_mp1, W_c, W_ut, W_uv};
        ushort_t* WTs[7]    = {WtT, WvT, Wmp0T, Wmp1T, WcT, WutT, WuvT};
        int Ks[7]           = {D_TEXT, D_VIS, 2 * D_EMB, D_EMB, D_EMB, D_EMB, D_EMB};
        int Nsrcs[7]        = {D_EMB, D_EMB, D_EMB, D_EMB, NC, NC, NC};
        int cum = 0;
        for (int g = 0; g < 7; g++) {
            a.W[g] = Ws[g]; a.WT[g] = WTs[g]; a.K[g] = Ks[g]; a.Nsrc[g] = Nsrcs[g];
            a.start[g] = cum; cum += Ks[g] * 128;
        }
        a.start[7] = cum;
        k_convAll<<<(cum + 255) / 256, 256, 0, stream>>>(a);
    }

    // ---- graph structure ----
    k_deg<<<(E + 255) / 256, 256, 0, stream>>>(esrc, edst, degO, degI, E);
    int nb = (N + 1023) / 1024;
    k_scan1<<<nb, 1024, 0, stream>>>(degI, offs, bsum, N);
    k_scan2<<<1, 1024, 0, stream>>>(bsum, nb);
    k_scan3<<<nb, 1024, 0, stream>>>(offs, bsum, degO, degI, invO, invI, N);
    k_place<<<(E + 255) / 256, 256, 0, stream>>>(esrc, edst, offs, cnt, invO, ep, E);

    const int gm = (N + 127) / 128;
    // modality encoders (fp32 in, relu, bf16 out)
    k_gemm<false, true, true><<<gm, 256, 0, stream>>>(text, nullptr, D_TEXT, WtT, D_TEXT, b_t, et, 128, 128, N);
    k_gemm<false, true, true><<<gm, 256, 0, stream>>>(vis,  nullptr, D_VIS,  WvT, D_VIS,  b_v, ev, 128, 128, N);
    // GCN layer 0: t = concat(et,ev) @ W_mp0 ; h = agg(t) + b_mp0
    k_gemm<true, false, true><<<gm, 256, 0, stream>>>(et, ev, D_EMB, Wmp0T, 2 * D_EMB, nullptr, tbuf, 128, 128, N);
    k_agg<<<(N + 3) / 4, 256, 0, stream>>>(tbuf, offs, degI, ep, invI, b_mp0, h, N);
    // GCN layer 1
    k_gemm<false, false, true><<<gm, 256, 0, stream>>>(h, nullptr, D_EMB, Wmp1T, D_EMB, nullptr, tbuf, 128, 128, N);
    k_agg<<<(N + 3) / 4, 256, 0, stream>>>(tbuf, offs, degI, ep, invI, b_mp1, h, N);

    // fused heads + combine (writes all 4 output segments)
    k_heads<<<gm, 256, 0, stream>>>(h, et, ev, WcT, WutT, WuvT, b_c, b_ut, b_uv,
                                    (float*)d_out, NC, N);
}